// Round 7
// baseline (377.524 us; speedup 1.0000x reference)
//
#include <hip/hip_runtime.h>
#include <hip/hip_bf16.h>
#include <math.h>

// Problem constants
#define N_   8
#define CIN_ 64
#define DIMS_ 64
#define NW_  8
#define T_   16
#define H_   64
#define W_   64
#define HW_  (H_ * W_)          // 4096
#define THW_ (T_ * HW_)         // 65536

typedef short bf16x8 __attribute__((ext_vector_type(8)));
typedef float f32x16 __attribute__((ext_vector_type(16)));

__device__ __forceinline__ unsigned short f2bf(float f) {
    union { float f; unsigned u; } a; a.f = f;
    unsigned r = a.u + 0x7fffu + ((a.u >> 16) & 1u);   // RNE
    return (unsigned short)(r >> 16);
}

// conv LDS geometry (halfword units)
#define CS8_ 8
#define HS8_ (66 * CS8_)        // 528
#define TS8_ (10 * HS8_)        // 5280
#define XB4_ (4 * TS8_)         // 21120 hw = 42240 B per x buffer (4 t-planes)
#define WB_  (28 * 64 * 8)      // 14336 hw = 28672 B per w buffer
// dynamic LDS layout (hw): x0 | x1 | w0 | w1 | junk | bnred
#define XOFF0_ 0
#define XOFF1_ XB4_                       // 21120
#define WOFF0_ (2 * XB4_)                 // 42240
#define WOFF1_ (2 * XB4_ + WB_)           // 56576
#define JUNK_  (2 * XB4_ + 2 * WB_)       // 70912 (512 hw)
#define BNRED_ (JUNK_ + 512)              // 71424 (256 hw = 128 f32)
#define DLS_BYTES_ ((BNRED_ + 256) * 2)   // 143360 B

__host__ __device__ constexpr int OXc(int tap) {
    int tt = tap > 26 ? 26 : tap;   // tap 27 = zero-weight pad -> any safe addr
    return (tt / 9) * TS8_ + ((tt % 9) / 3) * HS8_ + ((tt % 3) - 1) * CS8_;
}

// ---------------------------------------------------------------------------
// 1) fused: temporal std (ddof=1) + x -> xb bf16 [n][c8][t][h][w][8cin]
//    + SE weight transpose (first 75 flat blocks) + zero sums/pooled (block 0)
__global__ __launch_bounds__(512) void stdxb_kernel(
    const float* __restrict__ x, float* __restrict__ std_x,
    unsigned short* __restrict__ xb, float* __restrict__ sums,
    unsigned* __restrict__ pooled,
    const float* __restrict__ w1, const float* __restrict__ w2,
    float* __restrict__ w1t, float* __restrict__ w2t)
{
    __shared__ unsigned short xsl[16 * 64 * 8];   // [t][w][c] 16 KB
    const int h = blockIdx.x, c8 = blockIdx.y, n = blockIdx.z;
    const int tid = threadIdx.x;
    const int bf = blockIdx.x + (blockIdx.y << 6) + ((int)blockIdx.z << 9);
    if (bf == 0) {
        if (tid < 128) sums[tid] = 0.f;
        else if (tid < 384) pooled[tid - 128] = 0u;
    }
    if (bf < 75) {
        int i = bf * 512 + tid;
        if (i < 25600) {
            int k = i / 1600, c = (i / 25) % 64, tap = i % 25;
            w1t[(c * 25 + tap) * 16 + k] = w1[i];
        } else if (i < 38400) {
            int j = i - 25600;
            int o = j / 400, c = (j / 25) % 16, tap = j % 25;
            w2t[(c * 25 + tap) * 32 + o] = w2[j];
        }
    }
    const int c = tid >> 6, w = tid & 63;
    const int cin = c8 * 8 + c;
    const float* px = x + (((size_t)(n * 64 + cin)) << 16) + (h << 6) + w;
    float s = 0.f, s2 = 0.f;
#pragma unroll
    for (int t = 0; t < T_; ++t) {
        float v = px[t * HW_];
        s += v;
        s2 += v * v;
        xsl[(t << 9) + (w << 3) + c] = f2bf(v);
    }
    float var = (s2 - s * s * (1.0f / 16.0f)) * (1.0f / 15.0f);
    std_x[(((size_t)(n * 64 + cin)) << 12) + (h << 6) + w] = sqrtf(fmaxf(var, 0.f));
    __syncthreads();
    const int4* src = (const int4*)xsl;
    int4* dst = (int4*)(xb + ((size_t)((n * 8 + c8) * 16) << 12) * 8);
#pragma unroll
    for (int k = 0; k < 2; ++k) {
        int j = tid + (k << 9);
        int t = j >> 6, ww = j & 63;
        dst[((t << 6) + h) * 64 + ww] = src[j];
    }
}

// ---------------------------------------------------------------------------
// 2) SE conv1: block 256 = 64 ij x 4 c-quarters; 8 k per thread; LDS reduce
__global__ __launch_bounds__(256) void se_conv1c(const float* __restrict__ std_x,
        const float* __restrict__ w1t, const float* __restrict__ b1, float* __restrict__ h1) {
    __shared__ float red[3][64][8];
    const int n = blockIdx.y, ks = blockIdx.z * 8;
    const int iq = threadIdx.x & 63, cq = threadIdx.x >> 6;
    const int ij = blockIdx.x * 64 + iq;
    float acc[8];
#pragma unroll
    for (int q = 0; q < 8; ++q) acc[q] = 0.f;
    if (ij < 3600) {
        int i = ij / 60, j = ij - i * 60;
        const float* xn = std_x + (size_t)n * CIN_ * HW_ + i * W_ + j;
        for (int c = cq * 16; c < cq * 16 + 16; ++c) {
            const float* xc = xn + c * HW_;
            float xv[25];
#pragma unroll
            for (int u = 0; u < 5; ++u)
#pragma unroll
                for (int v = 0; v < 5; ++v) xv[u * 5 + v] = xc[u * W_ + v];
            const float* wc = w1t + c * 400 + ks;
#pragma unroll
            for (int tap = 0; tap < 25; ++tap)
#pragma unroll
                for (int q = 0; q < 8; ++q)
                    acc[q] = fmaf(xv[tap], wc[tap * 16 + q], acc[q]);
        }
    }
    if (cq > 0) {
#pragma unroll
        for (int q = 0; q < 8; ++q) red[cq - 1][iq][q] = acc[q];
    }
    __syncthreads();
    if (cq == 0 && ij < 3600) {
#pragma unroll
        for (int q = 0; q < 8; ++q) {
            float a = acc[q] + red[0][iq][q] + red[1][iq][q] + red[2][iq][q] + b1[ks + q];
            h1[((size_t)(n * 16 + ks + q)) * 3600 + ij] = fmaxf(a, 0.f);
        }
    }
}

// ---------------------------------------------------------------------------
// 3) SE conv2 + fused max-pool
__global__ __launch_bounds__(256) void se_conv2c(const float* __restrict__ h1,
        const float* __restrict__ w2t, const float* __restrict__ b2,
        unsigned* __restrict__ pooled) {
    __shared__ float red[3][64][8];
    const int n = blockIdx.y, os = blockIdx.z * 8;
    const int iq = threadIdx.x & 63, cq = threadIdx.x >> 6;
    const int ij = blockIdx.x * 64 + iq;   // exact 49*64 = 3136
    const int i = ij / 56, j = ij - i * 56;
    float acc[8];
#pragma unroll
    for (int q = 0; q < 8; ++q) acc[q] = 0.f;
    const float* xn = h1 + (size_t)n * 16 * 3600 + i * 60 + j;
    for (int c = cq * 4; c < cq * 4 + 4; ++c) {
        const float* xc = xn + c * 3600;
        float xv[25];
#pragma unroll
        for (int u = 0; u < 5; ++u)
#pragma unroll
            for (int v = 0; v < 5; ++v) xv[u * 5 + v] = xc[u * 60 + v];
        const float* wc = w2t + c * 800 + os;
#pragma unroll
        for (int tap = 0; tap < 25; ++tap)
#pragma unroll
            for (int q = 0; q < 8; ++q)
                acc[q] = fmaf(xv[tap], wc[tap * 32 + q], acc[q]);
    }
    if (cq > 0) {
#pragma unroll
        for (int q = 0; q < 8; ++q) red[cq - 1][iq][q] = acc[q];
    }
    __syncthreads();
    if (cq == 0) {
#pragma unroll
        for (int q = 0; q < 8; ++q) {
            float a = fmaxf(acc[q] + red[0][iq][q] + red[1][iq][q] + red[2][iq][q] + b2[os + q], 0.f);
#pragma unroll
            for (int m = 1; m < 64; m <<= 1) a = fmaxf(a, __shfl_xor(a, m, 64));
            if (iq == 0) atomicMax(&pooled[n * 32 + os + q], __float_as_uint(a));
        }
    }
}

// ---------------------------------------------------------------------------
// 6) dyn weights + head fused; block 0 writes dyn_b; first 64 blocks zero tap-27
__global__ __launch_bounds__(256) void dyn_w_head(
    const float* __restrict__ weights, const float* __restrict__ pooled,
    const float* __restrict__ lin_w, const float* __restrict__ lin_b,
    const float* __restrict__ biases, const int* __restrict__ epochs,
    unsigned short* __restrict__ wtb2, float* __restrict__ dyn_b) {
    __shared__ float slog[8][8];
    __shared__ float sphi[64];
    const int tid = threadIdx.x;
    const int e = epochs[0];
    const float tau = (e < 10) ? (30.0f - 2.9f * (float)e) : 1.0f;
    if (tid < 64) {
        int b = tid >> 3, m = tid & 7;
        float acc = lin_b[m];
#pragma unroll
        for (int k = 0; k < 32; ++k) acc += pooled[b * 32 + k] * lin_w[m * 32 + k];
        slog[b][m] = acc / tau;
    }
    __syncthreads();
    if (tid < 8) {
        float mx = slog[tid][0];
#pragma unroll
        for (int m = 1; m < 8; ++m) mx = fmaxf(mx, slog[tid][m]);
        float ex[8], ssum = 0.f;
#pragma unroll
        for (int m = 0; m < 8; ++m) { ex[m] = expf(slog[tid][m] - mx); ssum += ex[m]; }
        float inv = 1.0f / ssum;
#pragma unroll
        for (int m = 0; m < 8; ++m) sphi[tid * 8 + m] = ex[m] * inv;
    }
    __syncthreads();
    if (blockIdx.x < 64) {
        int b = blockIdx.x >> 3, c8 = blockIdx.x & 7;
        unsigned* dst = (unsigned*)(wtb2 + (size_t)b * 114688 + (size_t)(c8 * 28 + 27) * 512);
        dst[tid] = 0u;
    }
    if (blockIdx.x == 0) {
#pragma unroll
        for (int idx = tid; idx < 512; idx += 256) {
            int b = idx >> 6, d = idx & 63;
            float a = 0.f;
#pragma unroll
            for (int m = 0; m < 8; ++m) a += sphi[b * 8 + m] * biases[m * DIMS_ + d];
            dyn_b[idx] = a;
        }
    }
    int f = blockIdx.x * 256 + tid;   // 0..110591 = co*1728 + cin*27 + tap
    if (f >= 110592) return;
    int tap = f % 27, cin = (f / 27) & 63, co = f / 1728;
    float wv[8];
#pragma unroll
    for (int m = 0; m < 8; ++m) wv[m] = weights[(size_t)m * 110592 + f];
    size_t dbase = (size_t)(cin >> 3) * 14336 + tap * 512 + co * 8 + (cin & 7);
#pragma unroll
    for (int b = 0; b < 8; ++b) {
        float acc = 0.f;
#pragma unroll
        for (int m = 0; m < 8; ++m) acc += sphi[b * 8 + m] * wv[m];
        wtb2[(size_t)b * 114688 + dbase] = f2bf(acc);
    }
}

// ---------------------------------------------------------------------------
// 7) conv3d: 1024 thr = 16 waves, block = 2t x 8h x 64w outputs; x+w fully
//    double-buffered (143 KB dynamic LDS, 1 block/CU, 16 waves resident);
//    T3-min pipeline: prefetch next chunk, counted vmcnt(5) (never 0 mid-loop),
//    raw s_barriers. Wave = (t_loc, hrow); acc[2co][2sp] = 64 VGPR.
extern __shared__ unsigned short dls[];

__global__ __launch_bounds__(1024, 4) void conv3d_mfma6(
    const unsigned short* __restrict__ xb,     // [8][8][16][64][64][8]
    const unsigned short* __restrict__ wtb2,   // [8][8][28][64][8]
    const float* __restrict__ dynb,            // [8][64]
    float* __restrict__ y,                     // [8][64][16][64][64]
    float* __restrict__ sums)                  // [128]
{
    const int hb = blockIdx.x, tp2 = blockIdx.y, n = blockIdx.z;
    const int tid = threadIdx.x;
    const int lane = tid & 63, wid = tid >> 6;       // 16 waves
    const int lane31 = lane & 31, tau = lane >> 5;
    const int t_loc = wid >> 3, hrow = wid & 7;
    const int hbase = hb * 8, t2 = tp2 * 2;

    float* bnred = (float*)(dls + BNRED_);

    // zero both x buffers (halo rows / w-pads stay zero all chunks) + bnred
    for (int i = tid; i < (2 * XB4_) / 8; i += 1024)
        *(int4*)&dls[i * 8] = (int4){0, 0, 0, 0};
    if (tid < 128) bnred[tid] = 0.f;
    __syncthreads();   // nothing outstanding yet

    const unsigned short* xnb = xb + (size_t)n * 4194304;     // [c8][t][h][w][8]
    const unsigned short* wnb = wtb2 + (size_t)n * 114688;    // [c8][28][64][8]

    // stage chunk c8 into parity pb: uniform 5 global_load_lds per wave
    auto STAGE = [&](int c8, int pb) {
        unsigned short* xbuf = dls + (pb ? XOFF1_ : XOFF0_);
        unsigned short* wbuf = dls + (pb ? WOFF1_ : WOFF0_);
        unsigned short* junk = dls + JUNK_;
#pragma unroll
        for (int k = 0; k < 5; ++k) {
            int u = wid + (k << 4);              // wave-uniform, 0..79
            const unsigned short* gp;
            unsigned short* lp;
            if (u < 28) {                        // w tap u
                gp = wnb + ((size_t)c8 * 14336 + u * 512 + lane * 8);
                lp = wbuf + u * 512;
            } else if (u < 68) {                 // x unit
                int v = u - 28;                  // 0..39
                int tp = v / 10, hp = v - tp * 10;
                int gt = t2 + tp - 1, gh = hbase + hp - 1;
                bool ok = ((unsigned)gt < 16u) && ((unsigned)gh < 64u);
                gp = xnb + (ok ? (size_t)(((c8 * 16 + gt) * 64 + gh) * 512 + lane * 8)
                               : (size_t)(lane * 8));
                lp = ok ? (xbuf + tp * TS8_ + hp * HS8_ + CS8_) : junk;
            } else {                             // filler (keeps vmcnt uniform)
                gp = wnb + lane * 8;
                lp = junk;
            }
            __builtin_amdgcn_global_load_lds(
                (const __attribute__((address_space(1))) void*)gp,
                (__attribute__((address_space(3))) void*)lp, 16, 0, 0);
        }
    };

    f32x16 acc[2][2];
#pragma unroll
    for (int ci = 0; ci < 2; ++ci)
#pragma unroll
        for (int s = 0; s < 2; ++s)
            acc[ci][s] = (f32x16)(0.f);

    const int aBase = tau * 512 + lane31 * 8;
    const int bsp0 = t_loc * TS8_ + hrow * HS8_ + (1 + lane31) * CS8_;
    const int bsp1 = bsp0 + 32 * CS8_;

    STAGE(0, 0);

    for (int c8 = 0; c8 < 8; ++c8) {
        if (c8 < 7) {
            STAGE(c8 + 1, (c8 + 1) & 1);                       // prefetch next
            asm volatile("s_waitcnt vmcnt(5)" ::: "memory");   // chunk c8 landed
        } else {
            asm volatile("s_waitcnt vmcnt(0)" ::: "memory");
        }
        __builtin_amdgcn_sched_barrier(0);
        __builtin_amdgcn_s_barrier();          // chunk c8 visible to all waves
        __builtin_amdgcn_sched_barrier(0);

        const unsigned short* xsb = dls + ((c8 & 1) ? XOFF1_ : XOFF0_);
        const unsigned short* wlb = dls + ((c8 & 1) ? WOFF1_ : WOFF0_);
#pragma unroll
        for (int p = 0; p < 14; ++p) {
            const int xo = tau ? OXc(2 * p + 1) : OXc(2 * p);
            bf16x8 a0 = *(const bf16x8*)&wlb[p * 1024 + aBase];
            bf16x8 a1 = *(const bf16x8*)&wlb[p * 1024 + aBase + 256];
            bf16x8 b0 = *(const bf16x8*)&xsb[bsp0 + xo];
            bf16x8 b1 = *(const bf16x8*)&xsb[bsp1 + xo];
            acc[0][0] = __builtin_amdgcn_mfma_f32_32x32x16_bf16(a0, b0, acc[0][0], 0, 0, 0);
            acc[0][1] = __builtin_amdgcn_mfma_f32_32x32x16_bf16(a0, b1, acc[0][1], 0, 0, 0);
            acc[1][0] = __builtin_amdgcn_mfma_f32_32x32x16_bf16(a1, b0, acc[1][0], 0, 0, 0);
            acc[1][1] = __builtin_amdgcn_mfma_f32_32x32x16_bf16(a1, b1, acc[1][1], 0, 0, 0);
        }
        __builtin_amdgcn_s_barrier();          // protect parity reuse
    }

    // ---- epilogue: C/D col=lane31(w), row=(r&3)+8*(r>>2)+4*tau (+32*ci)
    const float* db = dynb + n * DIMS_;
    const int t_out = t2 + t_loc, h_out = hbase + hrow;
    const size_t ybase = (((size_t)(n * 64)) << 16) + ((size_t)t_out << 12) + ((size_t)h_out << 6);
#pragma unroll
    for (int ci = 0; ci < 2; ++ci) {
#pragma unroll
        for (int r = 0; r < 16; ++r) {
            const int co = 32 * ci + (r & 3) + 8 * (r >> 2) + 4 * tau;
            const float bco = db[co];
            float z0 = acc[ci][0][r] + bco;
            float z1 = acc[ci][1][r] + bco;
            y[ybase + ((size_t)co << 16) + lane31]      = z0;
            y[ybase + ((size_t)co << 16) + 32 + lane31] = z1;
            float ps = z0 + z1, ps2 = z0 * z0 + z1 * z1;
#pragma unroll
            for (int m = 1; m < 32; m <<= 1) {
                ps += __shfl_xor(ps, m, 64);
                ps2 += __shfl_xor(ps2, m, 64);
            }
            if (lane31 == 0) {
                atomicAdd(&bnred[co], ps);
                atomicAdd(&bnred[64 + co], ps2);
            }
        }
    }
    __syncthreads();
    if (tid < 128) atomicAdd(&sums[tid], bnred[tid]);
}

// ---------------------------------------------------------------------------
// 9) BN normalize + relu, float4, grid-stride, in place
__global__ void bn_norm4(const float* __restrict__ sums, const float* __restrict__ gamma,
                         const float* __restrict__ beta, float* __restrict__ y) {
    const float cnt = (float)(N_ * THW_);
    for (size_t idx = (size_t)blockIdx.x * 256 + threadIdx.x; idx < 8388608;
         idx += (size_t)4096 * 256) {
        int c = (int)((idx >> 14) & 63);
        float mean = sums[c] / cnt;
        float var = sums[64 + c] / cnt - mean * mean;
        float sc = gamma[c] * rsqrtf(var + 1e-5f);
        float sh = beta[c] - mean * sc;
        float4 v = ((float4*)y)[idx];
        v.x = fmaxf(fmaf(v.x, sc, sh), 0.f);
        v.y = fmaxf(fmaf(v.y, sc, sh), 0.f);
        v.z = fmaxf(fmaf(v.z, sc, sh), 0.f);
        v.w = fmaxf(fmaf(v.w, sc, sh), 0.f);
        ((float4*)y)[idx] = v;
    }
}

// ---------------------------------------------------------------------------
extern "C" void kernel_launch(void* const* d_in, const int* in_sizes, int n_in,
                              void* d_out, int out_size, void* d_ws, size_t ws_size,
                              hipStream_t stream) {
    const float* x       = (const float*)d_in[0];
    const float* weights = (const float*)d_in[1];
    const float* biases  = (const float*)d_in[2];
    const float* se_w1   = (const float*)d_in[3];
    const float* se_b1   = (const float*)d_in[4];
    const float* se_w2   = (const float*)d_in[5];
    const float* se_b2   = (const float*)d_in[6];
    const float* lin_w   = (const float*)d_in[7];
    const float* lin_b   = (const float*)d_in[8];
    const float* gamma   = (const float*)d_in[9];
    const float* beta    = (const float*)d_in[10];
    const int*   epochs  = (const int*)d_in[11];

    float* out = (float*)d_out;
    float* ws = (float*)d_ws;

    // workspace layout (float slots)
    const size_t STD_OFF  = 0;                        // 2,097,152
    const size_t H1_OFF   = STD_OFF + 2097152;        // 460,800
    const size_t SUMS_OFF = H1_OFF + 460800;          // 128
    const size_t POOL_OFF = SUMS_OFF + 128;           // 256
    const size_t PHI_OFF  = POOL_OFF + 256;           // 64 (unused)
    const size_t DYNB_OFF = PHI_OFF + 64;             // 512
    const size_t WTB_OFF  = DYNB_OFF + 512;           // 458,752 (bf16 x 917,504)
    const size_t W1T_OFF  = WTB_OFF + 458752;         // 25,600
    const size_t W2T_OFF  = W1T_OFF + 25600;          // 12,800
    const size_t XB_OFF   = W2T_OFF + 12800;          // 16,777,216 (bf16 x 33.5M)

    float* std_x  = ws + STD_OFF;
    float* h1     = ws + H1_OFF;
    float* sums   = ws + SUMS_OFF;
    float* pooled = ws + POOL_OFF;
    float* dynb   = ws + DYNB_OFF;
    unsigned short* wtb2 = (unsigned short*)(ws + WTB_OFF);
    float* w1t    = ws + W1T_OFF;
    float* w2t    = ws + W2T_OFF;
    unsigned short* xb = (unsigned short*)(ws + XB_OFF);

    // allow >64KB dynamic LDS for the conv kernel (idempotent, capture-safe)
    hipFuncSetAttribute((const void*)conv3d_mfma6,
                        hipFuncAttributeMaxDynamicSharedMemorySize, DLS_BYTES_);

    stdxb_kernel<<<dim3(64, 8, 8), 512, 0, stream>>>(
        x, std_x, xb, sums, (unsigned*)pooled, se_w1, se_w2, w1t, w2t);

    se_conv1c<<<dim3(57, 8, 2), 256, 0, stream>>>(std_x, w1t, se_b1, h1);
    se_conv2c<<<dim3(49, 8, 4), 256, 0, stream>>>(h1, w2t, se_b2, (unsigned*)pooled);

    dyn_w_head<<<432, 256, 0, stream>>>(weights, pooled, lin_w, lin_b, biases, epochs,
                                        wtb2, dynb);

    conv3d_mfma6<<<dim3(8, 8, 8), 1024, DLS_BYTES_, stream>>>(xb, wtb2, dynb, out, sums);

    bn_norm4<<<4096, 256, 0, stream>>>(sums, gamma, beta, out);
}